// Round 6
// baseline (2138.325 us; speedup 1.0000x reference)
//
#include <hip/hip_runtime.h>
#include <string.h>

#define B 4
#define N 16384
#define D 256
#define K 512
#define ITERS 10

typedef short short8 __attribute__((ext_vector_type(8)));
typedef float float4v __attribute__((ext_vector_type(4)));

// ---------------- host MT19937 exactly matching CPython random.seed(42); random.sample(range(16384), 512)
static void host_sample_inds(int* out) {
    static unsigned int mt[624];
    mt[0] = 19650218u;
    for (int i = 1; i < 624; i++)
        mt[i] = 1812433253u * (mt[i - 1] ^ (mt[i - 1] >> 30)) + (unsigned)i;
    {
        int i = 1, j = 0;
        for (int kk = 624; kk; kk--) {
            mt[i] = (mt[i] ^ ((mt[i - 1] ^ (mt[i - 1] >> 30)) * 1664525u)) + 42u + (unsigned)j;
            i++; j++;
            if (i >= 624) { mt[0] = mt[623]; i = 1; }
            if (j >= 1) j = 0;
        }
        for (int kk = 623; kk; kk--) {
            mt[i] = (mt[i] ^ ((mt[i - 1] ^ (mt[i - 1] >> 30)) * 1566083941u)) - (unsigned)i;
            i++;
            if (i >= 624) { mt[0] = mt[623]; i = 1; }
        }
        mt[0] = 0x80000000u;
    }
    static unsigned char seen[N];
    memset(seen, 0, sizeof(seen));
    int mti = 624;
    int got = 0;
    while (got < K) {
        if (mti >= 624) {
            for (int kk = 0; kk < 624; kk++) {
                unsigned int yy = (mt[kk] & 0x80000000u) | (mt[(kk + 1) % 624] & 0x7fffffffu);
                mt[kk] = mt[(kk + 397) % 624] ^ (yy >> 1) ^ ((yy & 1u) ? 0x9908b0dfu : 0u);
            }
            mti = 0;
        }
        unsigned int y = mt[mti++];
        y ^= y >> 11; y ^= (y << 7) & 0x9d2c5680u; y ^= (y << 15) & 0xefc60000u; y ^= y >> 18;
        unsigned int r = y >> 17;
        if (r >= (unsigned)N) continue;
        if (seen[r]) continue;
        seen[r] = 1;
        out[got++] = (int)r;
    }
}

__device__ inline void gload_lds16(const void* g, void* l) {
    __builtin_amdgcn_global_load_lds((const __attribute__((address_space(1))) void*)g,
                                     (__attribute__((address_space(3))) void*)l, 16, 0, 0);
}

__device__ inline unsigned bf16_rne(float f) {
    unsigned u = __float_as_uint(f);
    return (u + 0x7fffu + ((u >> 16) & 1u)) >> 16;
}

__device__ inline unsigned long long shfl_xor_u64(unsigned long long v, int off) {
    int lo = __shfl_xor((int)(unsigned)(v & 0xffffffffull), off);
    int hi = __shfl_xor((int)(unsigned)(v >> 32), off);
    return ((unsigned long long)(unsigned)hi << 32) | (unsigned)lo;
}

// =================== prep ===================

// also writes vT (k_transpose fused away)
__global__ void k_gather_v0(const float* __restrict__ x, const int* __restrict__ inds,
                            float* __restrict__ v, float* __restrict__ vT) {
    int bk = blockIdx.x; int b = bk / K, k = bk % K;
    int n = inds[k];
    int t = threadIdx.x;
    const float4* src = (const float4*)(x + ((size_t)b * N + n) * D);
    float4* dst = (float4*)(v + ((size_t)b * K + k) * D);
    float4 f = src[t];
    dst[t] = f;
    float comp[4] = {f.x, f.y, f.z, f.w};
    #pragma unroll
    for (int j = 0; j < 4; j++)
        vT[((size_t)b * D + t * 4 + j) * K + k] = comp[j];
}

// 4-deep pipelined row accumulation (loads hoisted; additions in original order)
__global__ void k_totsum(const float* __restrict__ x, float* __restrict__ totsum) {
    int b = blockIdx.y;
    int n0 = blockIdx.x * (N / 64);
    int t = threadIdx.x;
    const float* xb = x + (size_t)b * N * D;
    float s = 0.f;
    int n = n0;
    for (; n + 4 <= n0 + N / 64; n += 4) {
        float a0 = xb[(size_t)n * D + t];
        float a1 = xb[(size_t)(n + 1) * D + t];
        float a2 = xb[(size_t)(n + 2) * D + t];
        float a3 = xb[(size_t)(n + 3) * D + t];
        s += a0; s += a1; s += a2; s += a3;
    }
    for (; n < n0 + N / 64; n++) s += xb[(size_t)n * D + t];
    atomicAdd(&totsum[b * D + t], s);
}

// fused: rownorm + bf16 split + residual norm + lo norm. wave per row.
// v-mode (maxbuf != null): per-batch maxes via uint-punned atomicMax (k_errmax fused away)
//   maxbuf[b] = max v2 (sqrt at consumer), maxbuf[16+b] = max ||res||, maxbuf[32+b] = max ||lo||
__global__ void k_prep(const float* __restrict__ src, unsigned short* __restrict__ cat,
                       float* __restrict__ sq, float* __restrict__ resn,
                       float* __restrict__ lon, float* maxbuf) {
    int wave = threadIdx.x >> 6, lane = threadIdx.x & 63;
    int row = blockIdx.x * 4 + wave;
    float4 f = ((const float4*)(src + (size_t)row * D))[lane];
    float comp[4] = {f.x, f.y, f.z, f.w};
    unsigned short h[4], l[4];
    float r2 = 0.f, l2 = 0.f, n2 = 0.f;
    #pragma unroll
    for (int j = 0; j < 4; j++) {
        n2 += comp[j] * comp[j];
        unsigned hi = bf16_rne(comp[j]);
        float hif = __uint_as_float(hi << 16);
        float r = comp[j] - hif;            // exact in fp32
        unsigned lo = bf16_rne(r);
        float lof = __uint_as_float(lo << 16);
        float res = r - lof;                // dropped residual
        r2 += res * res;
        l2 += lof * lof;
        h[j] = (unsigned short)hi; l[j] = (unsigned short)lo;
    }
    unsigned short* orow = cat + (size_t)row * 512;
    *(ushort4*)&orow[lane * 4] = make_ushort4(h[0], h[1], h[2], h[3]);
    *(ushort4*)&orow[256 + lane * 4] = make_ushort4(l[0], l[1], l[2], l[3]);
    #pragma unroll
    for (int off = 32; off; off >>= 1) {
        r2 += __shfl_xor(r2, off);
        l2 += __shfl_xor(l2, off);
        n2 += __shfl_xor(n2, off);
    }
    if (lane == 0) {
        float rn = sqrtf(r2), ln = sqrtf(l2);
        sq[row] = n2; resn[row] = rn; lon[row] = ln;
        if (maxbuf) {
            int b = row >> 9;   // row / K
            atomicMax((unsigned int*)&maxbuf[b], __float_as_uint(n2));
            atomicMax((unsigned int*)&maxbuf[16 + b], __float_as_uint(rn));
            atomicMax((unsigned int*)&maxbuf[32 + b], __float_as_uint(ln));
        }
    }
}

// =================== fused MFMA GEMM + full 512-center top-2 + assign ===================
// 256x256 tile, 512 threads (8 waves, 2Mx4N), ring-of-4 32KB units (A-half+B-half),
// prefetch distance 3, counted vmcnt(8) (T3/T4 proven quadrant: 256sq + counted ring).
// Unit u: step n=u>>1 (ch=n/12, j=n%12 -> r1's validated 12-product schedule), k-half ks=u&1.
// Swizzle (r3-verified, 64B rows): global chunk g stored at slot g^((row>>1)&3);
// read slot = quad^((row>>1)&3) -> 2 lanes/bank within 16-lane phase = conflict-free.
// Numerics: same 24 (j,ks) half-products per center in same order as r1 -> identical dists.
__global__ __launch_bounds__(512, 2) void k_gemm_assign(
    const unsigned short* __restrict__ xcat, const unsigned short* __restrict__ vcat,
    const float* __restrict__ x2, const float* __restrict__ v2,
    const float* __restrict__ xres, const float* __restrict__ xlo,
    const float* __restrict__ maxbuf,
    int* __restrict__ assign, int* __restrict__ counts,
    int* __restrict__ refine_cnt, int* __restrict__ refine_pt) {
    __shared__ __align__(16) unsigned short ring[4][16384];   // per unit: A 16KB + B 16KB
    __shared__ float x2s[256];
    __shared__ float v2s[512];
    __shared__ unsigned long long candk[256][4][2];
    int b = blockIdx.y;
    int n0 = blockIdx.x * 256;
    int tid = threadIdx.x;
    int wv = tid >> 6, lane = tid & 63;
    int wr = wv >> 2, wc = wv & 3;          // 2 row-groups x 4 col-groups
    int quad = lane >> 4, l16 = lane & 15;
    const unsigned short* xb = xcat + ((size_t)b * N + n0) * 512;
    const unsigned short* vb0 = vcat + (size_t)b * K * 512;

    if (tid < 256) x2s[tid] = x2[b * N + n0 + tid];
    v2s[tid] = v2[b * K + tid];

    // staging meta: thread covers slots {tid, tid+512} of each 1024-slot (16B) half-tile
    int loff[2], srow[2], g8[2];
    #pragma unroll
    for (int i = 0; i < 2; i++) {
        int l = tid + i * 512;
        loff[i] = l * 8;
        srow[i] = l >> 2;
        g8[i] = (((l & 3) ^ ((l >> 3) & 3))) * 8;
    }

    float4v acc[8][4];
    #pragma unroll
    for (int i = 0; i < 8; i++)
        #pragma unroll
        for (int j = 0; j < 4; j++) acc[i][j] = (float4v){0.f, 0.f, 0.f, 0.f};

    // unit u -> (ch, j, ks) -> column bases (shorts) per r1's schedule:
    //   A: j<8 -> hi (j&3)*64 ; j>=8 -> lo 256+(j&3)*64
    //   B: j<4 -> vh ; 4<=j<8 -> vl(+256) ; j>=8 -> vh
    auto stage_u = [&](int u) {
        int n = u >> 1, ks = u & 1;
        int ch = n / 12, j = n - ch * 12;
        int k4 = (j & 3) << 6;
        int colA = ((j < 8) ? k4 : 256 + k4) + (ks << 5);
        int colB = ((j < 4) ? k4 : ((j < 8) ? 256 + k4 : k4)) + (ks << 5);
        const unsigned short* vbn = vb0 + ((size_t)ch << 17);   // ch*256*512
        unsigned short* dA = &ring[u & 3][0];
        unsigned short* dB = &ring[u & 3][8192];
        #pragma unroll
        for (int i = 0; i < 2; i++) {
            gload_lds16(xb + (size_t)srow[i] * 512 + colA + g8[i], dA + loff[i]);
            gload_lds16(vbn + (size_t)srow[i] * 512 + colB + g8[i], dB + loff[i]);
        }
    };

    auto compute_u = [&](int slot) {
        const unsigned short* As_ = &ring[slot][0];
        const unsigned short* Bs_ = &ring[slot][8192];
        short8 bf[4];
        #pragma unroll
        for (int fj = 0; fj < 4; fj++) {
            int rB = wc * 64 + fj * 16 + l16;
            bf[fj] = *(const short8*)&Bs_[(rB * 4 + (quad ^ ((rB >> 1) & 3))) * 8];
        }
        __builtin_amdgcn_s_setprio(1);
        #pragma unroll
        for (int fi = 0; fi < 8; fi++) {
            int rA = wr * 128 + fi * 16 + l16;
            short8 af = *(const short8*)&As_[(rA * 4 + (quad ^ ((rA >> 1) & 3))) * 8];
            #pragma unroll
            for (int fj = 0; fj < 4; fj++)
                acc[fi][fj] = __builtin_amdgcn_mfma_f32_16x16x32_bf16(
                    af, bf[fj], acc[fi][fj], 0, 0, 0);
        }
        __builtin_amdgcn_s_setprio(0);
    };

    // fold chunk ch (256 centers) into candk, zero acc
    auto fold = [&](int ch) {
        #pragma unroll
        for (int fi = 0; fi < 8; fi++) {
            #pragma unroll
            for (int r = 0; r < 4; r++) {
                int lrow = wr * 128 + fi * 16 + quad * 4 + r;
                float x2v = x2s[lrow];
                unsigned long long t1 = ~0ull, t2 = ~0ull;
                #pragma unroll
                for (int fj = 0; fj < 4; fj++) {
                    int cg = ch * 256 + wc * 64 + fj * 16 + l16;
                    float dist = fmaxf((x2v - 2.0f * acc[fi][fj][r]) + v2s[ch ? cg - 256 + 256 : cg], 0.0f);
                    // note: v2s indexed by global center id (0..511)
                    dist = fmaxf((x2v - 2.0f * acc[fi][fj][r]) + v2s[cg], 0.0f);
                    unsigned long long key =
                        ((unsigned long long)__float_as_uint(dist) << 32) | (unsigned)cg;
                    if (key < t1) { t2 = t1; t1 = key; }
                    else if (key < t2) { t2 = key; }
                }
                #pragma unroll
                for (int off = 1; off < 16; off <<= 1) {
                    unsigned long long o1 = shfl_xor_u64(t1, off);
                    unsigned long long o2 = shfl_xor_u64(t2, off);
                    unsigned long long mx = t1 > o1 ? t1 : o1;
                    t1 = t1 < o1 ? t1 : o1;
                    unsigned long long mn2 = t2 < o2 ? t2 : o2;
                    t2 = mx < mn2 ? mx : mn2;
                }
                if (l16 == 0) {
                    if (ch == 0) {
                        candk[lrow][wc][0] = t1; candk[lrow][wc][1] = t2;
                    } else {
                        unsigned long long a1 = candk[lrow][wc][0], a2 = candk[lrow][wc][1];
                        unsigned long long mx = a1 > t1 ? a1 : t1;
                        unsigned long long b1 = a1 < t1 ? a1 : t1;
                        unsigned long long mn2 = a2 < t2 ? a2 : t2;
                        unsigned long long b2 = mx < mn2 ? mx : mn2;
                        candk[lrow][wc][0] = b1; candk[lrow][wc][1] = b2;
                    }
                }
            }
        }
        #pragma unroll
        for (int fi = 0; fi < 8; fi++)
            #pragma unroll
            for (int fj = 0; fj < 4; fj++) acc[fi][fj] = (float4v){0.f, 0.f, 0.f, 0.f};
    };

    // prologue: stage units 0..2 (12 loads/thread in flight = steady state)
    stage_u(0); stage_u(1); stage_u(2);
    asm volatile("s_waitcnt lgkmcnt(0)" ::: "memory");   // x2s/v2s ds_writes visible
    __builtin_amdgcn_s_barrier();

    for (int u = 0; u < 45; u++) {
        asm volatile("s_waitcnt vmcnt(8)" ::: "memory"); // drains unit u; u+1,u+2 in flight
        __builtin_amdgcn_s_barrier();                    // all waves' unit-u data landed
        __builtin_amdgcn_sched_barrier(0);
        stage_u(u + 3);                                  // WAR-safe: slot (u-1)&3 reads done
        compute_u(u & 3);
        if (u == 23) fold(0);
    }
    asm volatile("s_waitcnt vmcnt(8)" ::: "memory");
    __builtin_amdgcn_s_barrier();
    __builtin_amdgcn_sched_barrier(0);
    compute_u(45 & 3);
    asm volatile("s_waitcnt vmcnt(4)" ::: "memory");
    __builtin_amdgcn_s_barrier();
    __builtin_amdgcn_sched_barrier(0);
    compute_u(46 & 3);
    asm volatile("s_waitcnt vmcnt(0)" ::: "memory");
    __builtin_amdgcn_s_barrier();
    __builtin_amdgcn_sched_barrier(0);
    compute_u(47 & 3);
    fold(1);

    __syncthreads();
    if (tid < 256) {
        unsigned long long m1 = candk[tid][0][0], m2 = candk[tid][0][1];
        #pragma unroll
        for (int g = 1; g < 4; g++) {
            unsigned long long o1 = candk[tid][g][0], o2 = candk[tid][g][1];
            unsigned long long mx = m1 > o1 ? m1 : o1;
            m1 = m1 < o1 ? m1 : o1;
            unsigned long long mn2 = m2 < o2 ? m2 : o2;
            m2 = mx < mn2 ? mx : mn2;
        }
        float bv1 = __uint_as_float((unsigned)(m1 >> 32));
        float bv2 = __uint_as_float((unsigned)(m2 >> 32));
        int bi1 = (int)(unsigned)(m1 & 0xffffffffull);
        int p = b * N + n0 + tid;
        assign[p] = bi1;
        atomicAdd(&counts[b * K + bi1], 1);
        // |dot err| <= xres*||v||max + ||x||*vresmax + xlo*vlomax (dropped xl*vl) [+ MFMA ~4e-4]
        float thr = 4.0f * (xres[p] * sqrtf(maxbuf[b]) + sqrtf(x2s[tid]) * maxbuf[16 + b]
                            + xlo[p] * maxbuf[32 + b]) + 4e-3f;
        if (bv2 - bv1 < thr) {
            int pos = atomicAdd(refine_cnt, 1);
            refine_pt[pos] = p;
        }
    }
}

// exact fp32 rescan over ALL 512 centers for flagged points; fixes counts on change
__global__ __launch_bounds__(256) void k_rescan(
    const float* __restrict__ x, const float* __restrict__ vT,
    const float* __restrict__ x2, const float* __restrict__ v2,
    const int* __restrict__ refine_cnt, const int* __restrict__ refine_pt,
    int* __restrict__ assign, int* __restrict__ counts) {
    __shared__ float xs[256];
    __shared__ float rv[256];
    __shared__ int ri[256];
    int cnt = *refine_cnt;
    int t = threadIdx.x;
    for (int i = blockIdx.x; i < cnt; i += gridDim.x) {
        int p = refine_pt[i];
        int b = p >> 14;
        xs[t] = x[(size_t)p * D + t];
        __syncthreads();
        const float* vtb = vT + (size_t)b * D * K;
        float s0 = 0.f, s1 = 0.f;
        for (int d = 0; d < D; d++) {
            float xd = xs[d];
            s0 = fmaf(xd, vtb[(size_t)d * K + t], s0);
            s1 = fmaf(xd, vtb[(size_t)d * K + 256 + t], s1);
        }
        float x2p = x2[p];
        float d0 = fmaxf((x2p - 2.0f * s0) + v2[b * K + t], 0.0f);
        float d1 = fmaxf((x2p - 2.0f * s1) + v2[b * K + 256 + t], 0.0f);
        float bv; int bi;
        if (d1 < d0) { bv = d1; bi = t + 256; } else { bv = d0; bi = t; }
        rv[t] = bv; ri[t] = bi;
        __syncthreads();
        for (int s = 128; s; s >>= 1) {
            if (t < s) {
                if (rv[t + s] < rv[t] || (rv[t + s] == rv[t] && ri[t + s] < ri[t])) {
                    rv[t] = rv[t + s]; ri[t] = ri[t + s];
                }
            }
            __syncthreads();
        }
        if (t == 0) {
            int old = assign[p];
            int neu = ri[0];
            if (neu != old) {
                assign[p] = neu;
                atomicSub(&counts[b * K + old], 1);
                atomicAdd(&counts[b * K + neu], 1);
            }
        }
        __syncthreads();
    }
}

// =================== membership -> new centers (proven) ===================

__global__ __launch_bounds__(256) void k_scatter(
    const int* __restrict__ assign, const int* __restrict__ counts,
    int* __restrict__ cursor, int* __restrict__ order) {
    __shared__ int offs[K];
    int b = blockIdx.y;
    if (threadIdx.x < 64) {
        int lane = threadIdx.x;
        int pre[8]; int s = 0;
        #pragma unroll
        for (int j = 0; j < 8; j++) { pre[j] = s; s += counts[b * K + lane * 8 + j]; }
        int inc = s;
        #pragma unroll
        for (int off = 1; off < 64; off <<= 1) {
            int o = __shfl_up(inc, off);
            if (lane >= off) inc += o;
        }
        int excl = inc - s;
        #pragma unroll
        for (int j = 0; j < 8; j++) offs[lane * 8 + j] = excl + pre[j];
    }
    __syncthreads();
    int n = blockIdx.x * 256 + threadIdx.x;
    int a = assign[b * N + n];
    int pos = atomicAdd(&cursor[b * K + a], 1);
    order[b * N + offs[a] + pos] = n;
}

// inner member loop 4-deep pipelined; also writes vT (k_transpose fused away)
__global__ __launch_bounds__(256) void k_sumdiv(
    const float* __restrict__ x, const int* __restrict__ counts,
    const int* __restrict__ order, const float* __restrict__ totsum,
    float* __restrict__ v, float* __restrict__ vT) {
    __shared__ int sh[256];
    __shared__ int ord[256];
    int t = threadIdx.x;
    int b = blockIdx.y, k = blockIdx.x;
    const int* cb = counts + b * K;
    int partial = 0;
    for (int j = t; j < k; j += 256) partial += cb[j];
    sh[t] = partial; __syncthreads();
    for (int s = 128; s; s >>= 1) { if (t < s) sh[t] += sh[t + s]; __syncthreads(); }
    int off = sh[0];
    int cnt = cb[k];
    const float* xb = x + (size_t)b * N * D;
    float acc = 0.f;
    for (int m0 = 0; m0 < cnt; m0 += 256) {
        int mm = min(256, cnt - m0);
        if (t < mm) ord[t] = order[b * N + off + m0 + t];
        __syncthreads();
        int m = 0;
        for (; m + 4 <= mm; m += 4) {
            int i0 = ord[m], i1 = ord[m + 1], i2 = ord[m + 2], i3 = ord[m + 3];
            float a0 = xb[(size_t)i0 * D + t];
            float a1 = xb[(size_t)i1 * D + t];
            float a2 = xb[(size_t)i2 * D + t];
            float a3 = xb[(size_t)i3 * D + t];
            acc += a0; acc += a1; acc += a2; acc += a3;
        }
        for (; m < mm; m++) {
            int n = ord[m];
            acc += xb[(size_t)n * D + t];
        }
        __syncthreads();
    }
    float out;
    if (cnt > 0) out = acc * (1.0f / (float)cnt);
    else out = totsum[b * D + t];
    v[((size_t)b * K + k) * D + t] = out;
    vT[((size_t)b * D + t) * K + k] = out;
}

__global__ void k_write_u(const int* __restrict__ assign, float* __restrict__ uout) {
    int idx = blockIdx.x * 256 + threadIdx.x;
    int a = assign[idx];
    uout[(size_t)idx * K + a] = 1.0f;
}

__global__ void k_copy_v(const float* __restrict__ v, float* __restrict__ out) {
    int idx = blockIdx.x * 256 + threadIdx.x;
    ((float4*)out)[idx] = ((const float4*)v)[idx];
}

extern "C" void kernel_launch(void* const* d_in, const int* in_sizes, int n_in,
                              void* d_out, int out_size, void* d_ws, size_t ws_size,
                              hipStream_t stream) {
    const float* x = (const float*)d_in[0];
    float* out = (float*)d_out;
    char* ws = (char*)d_ws;

    // ---- ws: proven-small footprint (<3.0 MB) ----
    size_t off = 0;
    float* v      = (float*)(ws + off); off += (size_t)B * K * D * 4;
    float* x2     = (float*)(ws + off); off += (size_t)B * N * 4;
    float* v2     = (float*)(ws + off); off += (size_t)B * K * 4;
    float* totsum = (float*)(ws + off); off += (size_t)B * D * 4;
    int* assign   = (int*)(ws + off);   off += (size_t)B * N * 4;
    int* order    = (int*)(ws + off);   off += (size_t)B * N * 4;
    int* inds     = (int*)(ws + off);   off += 4096;
    // contiguous zero-region: counts + cursor + refine_cnt + maxbuf (one memset)
    int* counts   = (int*)(ws + off);   off += (size_t)B * K * 4;
    int* cursor   = (int*)(ws + off);   off += (size_t)B * K * 4;
    int* refine_cnt = (int*)(ws + off); off += 256;
    float* maxbuf = (float*)(ws + off); off += 256;   // [b]=max v2, [16+b]=max||res||, [32+b]=max||lo||
    size_t zero_bytes = 2 * (size_t)B * K * 4 + 512;

    // ---- big scratch in d_out u-region (134 MB; proven home) ----
    char* ob = (char*)out;
    size_t oboff = 0;
    unsigned short* xcat = (unsigned short*)(ob + oboff); oboff += (size_t)B * N * 512 * 2;  // 64 MiB
    int* refine_pt = (int*)(ob + oboff);    oboff += (size_t)B * N * 4;                      // 256 KiB
    float* vT      = (float*)(ob + oboff);  oboff += (size_t)B * K * D * 4;                  // 2 MiB
    float* xres    = (float*)(ob + oboff);  oboff += (size_t)B * N * 4;                      // 256 KiB
    float* xlo     = (float*)(ob + oboff);  oboff += (size_t)B * N * 4;                      // 256 KiB
    float* vres    = (float*)(ob + oboff);  oboff += (size_t)B * K * 4;                      // 8 KiB (scratch)
    float* vlo     = (float*)(ob + oboff);  oboff += (size_t)B * K * 4;                      // 8 KiB (scratch)
    unsigned short* vcat = (unsigned short*)(out + (size_t)B * N * K);  // v-region, 2 MiB exact

    static int h_inds[K];
    host_sample_inds(h_inds);
    hipMemcpyAsync(inds, h_inds, K * sizeof(int), hipMemcpyHostToDevice, stream);

    hipMemsetAsync(totsum, 0, (size_t)B * D * 4, stream);
    k_gather_v0<<<B * K, 64, 0, stream>>>(x, inds, v, vT);
    k_totsum<<<dim3(64, B), 256, 0, stream>>>(x, totsum);
    k_prep<<<(B * N) / 4, 256, 0, stream>>>(x, xcat, x2, xres, xlo, nullptr);

    for (int it = 0; it < ITERS; it++) {
        hipMemsetAsync(counts, 0, zero_bytes, stream);   // counts+cursor+refine_cnt+maxbuf
        k_prep<<<(B * K) / 4, 256, 0, stream>>>(v, vcat, v2, vres, vlo, maxbuf);
        k_gemm_assign<<<dim3(N / 256, B), 512, 0, stream>>>(
            xcat, vcat, x2, v2, xres, xlo, maxbuf,
            assign, counts, refine_cnt, refine_pt);
        k_rescan<<<1024, 256, 0, stream>>>(x, vT, x2, v2, refine_cnt, refine_pt,
                                           assign, counts);
        k_scatter<<<dim3(N / 256, B), 256, 0, stream>>>(assign, counts, cursor, order);
        k_sumdiv<<<dim3(K, B), 256, 0, stream>>>(x, counts, order, totsum, v, vT);
    }

    hipMemsetAsync(out, 0, (size_t)B * N * K * 4, stream);
    k_write_u<<<(B * N) / 256, 256, 0, stream>>>(assign, out);
    k_copy_v<<<(B * K * D) / 1024, 256, 0, stream>>>(v, out + (size_t)B * N * K);
}